// Round 1
// baseline (3086.525 us; speedup 1.0000x reference)
//
#include <hip/hip_runtime.h>
#include <math.h>

// GCN_homo: h = relu(D^-1/2 (A+I) D^-1/2 (x@Wg) + bg); MLP 16->16->32->1; sigmoid.
// N=100000, F=512, E=3200000. All fp32; edge_index int32 (JAX x64 disabled).

static constexpr int F = 512;
static constexpr int C = 16;

// K1: xw[row][0..15] = x[row] @ Wg.  One thread per row; Wg via uniform (scalar) loads.
__global__ __launch_bounds__(256) void k_xw(const float* __restrict__ x,
                                            const float* __restrict__ Wg,
                                            float* __restrict__ xw, int n)
{
    int row = blockIdx.x * 256 + threadIdx.x;
    if (row >= n) return;
    float acc[C];
#pragma unroll
    for (int c = 0; c < C; ++c) acc[c] = 0.f;
    const float4* xr = (const float4*)(x + (size_t)row * F);
#pragma unroll 4
    for (int k4 = 0; k4 < F / 4; ++k4) {
        float4 xv = xr[k4];
        const float* w = Wg + k4 * 4 * C;  // uniform address -> s_load
#pragma unroll
        for (int j = 0; j < 4; ++j) {
            float xs = (j == 0) ? xv.x : (j == 1) ? xv.y : (j == 2) ? xv.z : xv.w;
#pragma unroll
            for (int c = 0; c < C; ++c)
                acc[c] = fmaf(xs, w[j * C + c], acc[c]);
        }
    }
    float4* o = (float4*)(xw + (size_t)row * C);
#pragma unroll
    for (int q = 0; q < 4; ++q)
        o[q] = make_float4(acc[4 * q + 0], acc[4 * q + 1], acc[4 * q + 2], acc[4 * q + 3]);
}

// K2a: deg = 1 (self-loop)
__global__ __launch_bounds__(256) void k_deg_init(float* __restrict__ deg, int n)
{
    int i = blockIdx.x * 256 + threadIdx.x;
    if (i < n) deg[i] = 1.0f;
}

// K2b: deg[col[e]] += 1
__global__ __launch_bounds__(256) void k_deg_count(const int* __restrict__ col,
                                                   float* __restrict__ deg, int e)
{
    int i = blockIdx.x * 256 + threadIdx.x;
    if (i < e) atomicAdd(&deg[col[i]], 1.0f);
}

// K3: dinv = rsqrt(deg) (stored back into deg); y = xw*dinv (in place); agg = y (self-loop init)
__global__ __launch_bounds__(256) void k_scale_init(float* __restrict__ xw,
                                                    float* __restrict__ deg,
                                                    float* __restrict__ agg, int n)
{
    int i = blockIdx.x * 256 + threadIdx.x;
    if (i >= n) return;
    float di = rsqrtf(deg[i]);  // deg >= 1 always (self-loop)
    deg[i] = di;                // deg buffer now holds dinv
    float4* yr = (float4*)(xw + (size_t)i * C);
    float4* ar = (float4*)(agg + (size_t)i * C);
#pragma unroll
    for (int q = 0; q < 4; ++q) {
        float4 v = yr[q];
        v.x *= di; v.y *= di; v.z *= di; v.w *= di;
        yr[q] = v;
        ar[q] = v;
    }
}

// K4: per edge: agg[col] += y[row]  (16 fp32 atomics; dinv[col] factored into K5)
__global__ __launch_bounds__(256) void k_edge(const int* __restrict__ idx,
                                              const float* __restrict__ y,
                                              float* __restrict__ agg, int E)
{
    int i = blockIdx.x * 256 + threadIdx.x;
    if (i >= E) return;
    int r = idx[i];          // source
    int c = idx[E + i];      // target
    const float4* yr = (const float4*)(y + (size_t)r * C);
    float* a = agg + (size_t)c * C;
#pragma unroll
    for (int q = 0; q < 4; ++q) {
        float4 v = yr[q];
        atomicAdd(a + 4 * q + 0, v.x);
        atomicAdd(a + 4 * q + 1, v.y);
        atomicAdd(a + 4 * q + 2, v.z);
        atomicAdd(a + 4 * q + 3, v.w);
    }
}

// K5: h = relu(dinv*agg + bg); h1 = relu(h@W1+b1); h2 = relu(h1@W2+b2); out = sigmoid(h2@W3+b3)
__global__ __launch_bounds__(256) void k_mlp(const float* __restrict__ agg,
                                             const float* __restrict__ dinv,
                                             const float* __restrict__ bg,
                                             const float* __restrict__ W1,
                                             const float* __restrict__ b1,
                                             const float* __restrict__ W2,
                                             const float* __restrict__ b2,
                                             const float* __restrict__ W3,
                                             const float* __restrict__ b3,
                                             float* __restrict__ out, int n)
{
    int i = blockIdx.x * 256 + threadIdx.x;
    if (i >= n) return;
    float di = dinv[i];
    float h[16];
    const float4* ar = (const float4*)(agg + (size_t)i * C);
#pragma unroll
    for (int q = 0; q < 4; ++q) {
        float4 v = ar[q];
        h[4 * q + 0] = fmaxf(fmaf(v.x, di, bg[4 * q + 0]), 0.f);
        h[4 * q + 1] = fmaxf(fmaf(v.y, di, bg[4 * q + 1]), 0.f);
        h[4 * q + 2] = fmaxf(fmaf(v.z, di, bg[4 * q + 2]), 0.f);
        h[4 * q + 3] = fmaxf(fmaf(v.w, di, bg[4 * q + 3]), 0.f);
    }
    float h1[16];
#pragma unroll
    for (int c = 0; c < 16; ++c) {
        float s = b1[c];
#pragma unroll
        for (int k = 0; k < 16; ++k) s = fmaf(h[k], W1[k * 16 + c], s);
        h1[c] = fmaxf(s, 0.f);
    }
    float h2[32];
#pragma unroll
    for (int c = 0; c < 32; ++c) {
        float s = b2[c];
#pragma unroll
        for (int k = 0; k < 16; ++k) s = fmaf(h1[k], W2[k * 32 + c], s);
        h2[c] = fmaxf(s, 0.f);
    }
    float s = b3[0];
#pragma unroll
    for (int k = 0; k < 32; ++k) s = fmaf(h2[k], W3[k], s);
    out[i] = 1.f / (1.f + expf(-s));
}

extern "C" void kernel_launch(void* const* d_in, const int* in_sizes, int n_in,
                              void* d_out, int out_size, void* d_ws, size_t ws_size,
                              hipStream_t stream)
{
    const float* x  = (const float*)d_in[0];
    const int*   ei = (const int*)d_in[1];   // [2,E] int32: row at [e], col at [E+e]
    const float* Wg = (const float*)d_in[2];
    const float* bg = (const float*)d_in[3];
    const float* W1 = (const float*)d_in[4];
    const float* b1 = (const float*)d_in[5];
    const float* W2 = (const float*)d_in[6];
    const float* b2 = (const float*)d_in[7];
    const float* W3 = (const float*)d_in[8];
    const float* b3 = (const float*)d_in[9];
    float* out = (float*)d_out;

    int n = in_sizes[0] / F;       // 100000
    int E = in_sizes[1] / 2;       // 3200000

    // Workspace layout (all 16B-aligned): xw/y [n*16], agg [n*16], deg/dinv [n]
    char* ws = (char*)d_ws;
    float* xw  = (float*)ws;
    float* agg = (float*)(ws + (size_t)n * C * sizeof(float));
    float* deg = (float*)(ws + (size_t)n * C * sizeof(float) * 2);

    int gb = (n + 255) / 256;
    int ge = (E + 255) / 256;

    k_xw<<<gb, 256, 0, stream>>>(x, Wg, xw, n);
    k_deg_init<<<gb, 256, 0, stream>>>(deg, n);
    k_deg_count<<<ge, 256, 0, stream>>>(ei + E, deg, E);
    k_scale_init<<<gb, 256, 0, stream>>>(xw, deg, agg, n);
    k_edge<<<ge, 256, 0, stream>>>(ei, xw, agg, E);
    k_mlp<<<gb, 256, 0, stream>>>(agg, deg, bg, W1, b1, W2, b2, W3, b3, out, n);
}

// Round 2
// 763.814 us; speedup vs baseline: 4.0409x; 4.0409x over previous
//
#include <hip/hip_runtime.h>
#include <math.h>

// GCN_homo: h = relu(D^-1/2 (A+I) D^-1/2 (x@Wg) + bg); MLP 16->16->32->1; sigmoid.
// N=100000, F=512, E=3200000. fp32; edge_index int32.
// R2: replace 51.2M fp32 atomics (19.7 G atomics/s HW budget => 2.6 ms) with
// device-built CSR (3.2M int atomics) + atomic-free per-node gather.

static constexpr int F = 512;
static constexpr int C = 16;

// K1: xw[row][0..15] = x[row] @ Wg. One thread per row; Wg via uniform loads.
__global__ __launch_bounds__(256) void k_xw(const float* __restrict__ x,
                                            const float* __restrict__ Wg,
                                            float* __restrict__ xw, int n)
{
    int row = blockIdx.x * 256 + threadIdx.x;
    if (row >= n) return;
    float acc[C];
#pragma unroll
    for (int c = 0; c < C; ++c) acc[c] = 0.f;
    const float4* xr = (const float4*)(x + (size_t)row * F);
#pragma unroll 4
    for (int k4 = 0; k4 < F / 4; ++k4) {
        float4 xv = xr[k4];
        const float* w = Wg + k4 * 4 * C;  // uniform -> s_load
#pragma unroll
        for (int j = 0; j < 4; ++j) {
            float xs = (j == 0) ? xv.x : (j == 1) ? xv.y : (j == 2) ? xv.z : xv.w;
#pragma unroll
            for (int c = 0; c < C; ++c)
                acc[c] = fmaf(xs, w[j * C + c], acc[c]);
        }
    }
    float4* o = (float4*)(xw + (size_t)row * C);
#pragma unroll
    for (int q = 0; q < 4; ++q)
        o[q] = make_float4(acc[4 * q + 0], acc[4 * q + 1], acc[4 * q + 2], acc[4 * q + 3]);
}

__global__ __launch_bounds__(256) void k_zero(int* __restrict__ cnt, int n)
{
    int i = blockIdx.x * 256 + threadIdx.x;
    if (i < n) cnt[i] = 0;
}

// Counting-sort pass A: per-target rank of each edge. 3.2M int atomics.
__global__ __launch_bounds__(256) void k_rank(const int* __restrict__ col,
                                              int* __restrict__ cnt,
                                              int* __restrict__ rank, int E)
{
    int e = blockIdx.x * 256 + threadIdx.x;
    if (e >= E) return;
    rank[e] = atomicAdd(&cnt[col[e]], 1);
}

// Pass B: exclusive prefix sum of cnt[0..n) -> starts. One 1024-thread block.
__global__ __launch_bounds__(1024) void k_scan(const int* __restrict__ cnt,
                                               int* __restrict__ starts, int n)
{
    __shared__ int part[1024];
    int t = threadIdx.x;
    int chunk = (n + 1023) >> 10;
    int lo = t * chunk;
    int hi = lo + chunk; if (hi > n) hi = n;
    int s = 0;
    for (int i = lo; i < hi; ++i) s += cnt[i];
    part[t] = s;
    __syncthreads();
    for (int d = 1; d < 1024; d <<= 1) {
        int v = (t >= d) ? part[t - d] : 0;
        __syncthreads();
        part[t] += v;
        __syncthreads();
    }
    int off = part[t] - s;  // exclusive prefix of this chunk
    for (int i = lo; i < hi; ++i) { starts[i] = off; off += cnt[i]; }
}

// Pass C: scatter source indices into CSR order. No atomics.
__global__ __launch_bounds__(256) void k_scatter(const int* __restrict__ ei,
                                                 const int* __restrict__ rank,
                                                 const int* __restrict__ starts,
                                                 int* __restrict__ srcs, int E)
{
    int e = blockIdx.x * 256 + threadIdx.x;
    if (e >= E) return;
    int r = ei[e];        // source
    int c = ei[E + e];    // target
    srcs[starts[c] + rank[e]] = r;
}

// y = xw * dinv (in place); dinv = rsqrt(deg), deg = cnt + 1 (self-loop).
__global__ __launch_bounds__(256) void k_scale(float* __restrict__ xw,
                                               const int* __restrict__ cnt,
                                               float* __restrict__ dinv, int n)
{
    int i = blockIdx.x * 256 + threadIdx.x;
    if (i >= n) return;
    float di = rsqrtf((float)(cnt[i] + 1));
    dinv[i] = di;
    float4* yr = (float4*)(xw + (size_t)i * C);
#pragma unroll
    for (int q = 0; q < 4; ++q) {
        float4 v = yr[q];
        v.x *= di; v.y *= di; v.z *= di; v.w *= di;
        yr[q] = v;
    }
}

// Gather: 4 threads per node, one float4 channel-chunk each. Coalesced 64B
// read of y[src] per edge across the 4-lane group. Fuses dinv/bias/relu.
__global__ __launch_bounds__(256) void k_gather(const float* __restrict__ y,
                                                const int* __restrict__ srcs,
                                                const int* __restrict__ starts,
                                                const int* __restrict__ cnt,
                                                const float* __restrict__ dinv,
                                                const float* __restrict__ bg,
                                                float* __restrict__ h, int n)
{
    int tid = blockIdx.x * 256 + threadIdx.x;
    int i = tid >> 2;
    if (i >= n) return;
    int q = tid & 3;
    float4 acc = ((const float4*)(y + (size_t)i * C))[q];  // self-loop term
    int beg = starts[i];
    int end = beg + cnt[i];
    for (int e = beg; e < end; ++e) {
        int s = srcs[e];
        float4 v = ((const float4*)(y + (size_t)s * C))[q];
        acc.x += v.x; acc.y += v.y; acc.z += v.z; acc.w += v.w;
    }
    float di = dinv[i];
    const float* bq = bg + q * 4;
    float4 r;
    r.x = fmaxf(fmaf(acc.x, di, bq[0]), 0.f);
    r.y = fmaxf(fmaf(acc.y, di, bq[1]), 0.f);
    r.z = fmaxf(fmaf(acc.z, di, bq[2]), 0.f);
    r.w = fmaxf(fmaf(acc.w, di, bq[3]), 0.f);
    ((float4*)(h + (size_t)i * C))[q] = r;
}

// MLP: h1 = relu(h@W1+b1); h2 = relu(h1@W2+b2); out = sigmoid(h2@W3+b3)
__global__ __launch_bounds__(256) void k_mlp(const float* __restrict__ hbuf,
                                             const float* __restrict__ W1,
                                             const float* __restrict__ b1,
                                             const float* __restrict__ W2,
                                             const float* __restrict__ b2,
                                             const float* __restrict__ W3,
                                             const float* __restrict__ b3,
                                             float* __restrict__ out, int n)
{
    int i = blockIdx.x * 256 + threadIdx.x;
    if (i >= n) return;
    float h[16];
    const float4* hr = (const float4*)(hbuf + (size_t)i * C);
#pragma unroll
    for (int q = 0; q < 4; ++q) {
        float4 v = hr[q];
        h[4 * q + 0] = v.x; h[4 * q + 1] = v.y; h[4 * q + 2] = v.z; h[4 * q + 3] = v.w;
    }
    float h1[16];
#pragma unroll
    for (int c = 0; c < 16; ++c) {
        float s = b1[c];
#pragma unroll
        for (int k = 0; k < 16; ++k) s = fmaf(h[k], W1[k * 16 + c], s);
        h1[c] = fmaxf(s, 0.f);
    }
    float h2[32];
#pragma unroll
    for (int c = 0; c < 32; ++c) {
        float s = b2[c];
#pragma unroll
        for (int k = 0; k < 16; ++k) s = fmaf(h1[k], W2[k * 32 + c], s);
        h2[c] = fmaxf(s, 0.f);
    }
    float s = b3[0];
#pragma unroll
    for (int k = 0; k < 32; ++k) s = fmaf(h2[k], W3[k], s);
    out[i] = 1.f / (1.f + expf(-s));
}

extern "C" void kernel_launch(void* const* d_in, const int* in_sizes, int n_in,
                              void* d_out, int out_size, void* d_ws, size_t ws_size,
                              hipStream_t stream)
{
    const float* x  = (const float*)d_in[0];
    const int*   ei = (const int*)d_in[1];   // [2,E]: row at [e], col at [E+e]
    const float* Wg = (const float*)d_in[2];
    const float* bg = (const float*)d_in[3];
    const float* W1 = (const float*)d_in[4];
    const float* b1 = (const float*)d_in[5];
    const float* W2 = (const float*)d_in[6];
    const float* b2 = (const float*)d_in[7];
    const float* W3 = (const float*)d_in[8];
    const float* b3 = (const float*)d_in[9];
    float* out = (float*)d_out;

    int n = in_sizes[0] / F;   // 100000
    int E = in_sizes[1] / 2;   // 3200000

    // ws layout (16B aligned): y[n*16] f32 | h[n*16] f32 | rank[E] i32 |
    //                          srcs[E] i32 | cnt[n] i32 | starts[n] i32 | dinv[n] f32
    char* ws = (char*)d_ws;
    size_t off = 0;
    float* y      = (float*)(ws + off); off += (size_t)n * C * sizeof(float);
    float* h      = (float*)(ws + off); off += (size_t)n * C * sizeof(float);
    int*   rank   = (int*)  (ws + off); off += (size_t)E * sizeof(int);
    int*   srcs   = (int*)  (ws + off); off += (size_t)E * sizeof(int);
    int*   cnt    = (int*)  (ws + off); off += (size_t)((n + 3) & ~3) * sizeof(int);
    int*   starts = (int*)  (ws + off); off += (size_t)((n + 3) & ~3) * sizeof(int);
    float* dinv   = (float*)(ws + off);

    int gb = (n + 255) / 256;
    int ge = (E + 255) / 256;
    int gg = (n * 4 + 255) / 256;

    k_xw<<<gb, 256, 0, stream>>>(x, Wg, y, n);
    k_zero<<<gb, 256, 0, stream>>>(cnt, n);
    k_rank<<<ge, 256, 0, stream>>>(ei + E, cnt, rank, E);
    k_scan<<<1, 1024, 0, stream>>>(cnt, starts, n);
    k_scatter<<<ge, 256, 0, stream>>>(ei, rank, starts, srcs, E);
    k_scale<<<gb, 256, 0, stream>>>(y, cnt, dinv, n);
    k_gather<<<gg, 256, 0, stream>>>(y, srcs, starts, cnt, dinv, bg, h, n);
    k_mlp<<<gb, 256, 0, stream>>>(h, W1, b1, W2, b2, W3, b3, out, n);
}

// Round 3
// 606.486 us; speedup vs baseline: 5.0892x; 1.2594x over previous
//
#include <hip/hip_runtime.h>
#include <math.h>

// GCN_homo: h = relu(D^-1/2 (A+I) D^-1/2 (x@Wg) + bg); MLP 16->16->32->1; sigmoid.
// N=100000, F=512, E=3200000. fp32; edge_index int32.
// R3: replace single-block scan (161 us, 0.16% occupancy) with 3-kernel
// hierarchical scan; int4 srcs loads in gather; fuse cnt-zeroing into k_xw.

static constexpr int F = 512;
static constexpr int C = 16;
static constexpr int SCAN_TILE = 1024;  // elements per block in scan (256 thr x 4)

// K1: xw[row] = x[row] @ Wg; also zeroes cnt[row].
__global__ __launch_bounds__(256) void k_xw(const float* __restrict__ x,
                                            const float* __restrict__ Wg,
                                            float* __restrict__ xw,
                                            int* __restrict__ cnt, int n)
{
    int row = blockIdx.x * 256 + threadIdx.x;
    if (row >= n) return;
    cnt[row] = 0;
    float acc[C];
#pragma unroll
    for (int c = 0; c < C; ++c) acc[c] = 0.f;
    const float4* xr = (const float4*)(x + (size_t)row * F);
#pragma unroll 4
    for (int k4 = 0; k4 < F / 4; ++k4) {
        float4 xv = xr[k4];
        const float* w = Wg + k4 * 4 * C;  // uniform -> s_load
#pragma unroll
        for (int j = 0; j < 4; ++j) {
            float xs = (j == 0) ? xv.x : (j == 1) ? xv.y : (j == 2) ? xv.z : xv.w;
#pragma unroll
            for (int c = 0; c < C; ++c)
                acc[c] = fmaf(xs, w[j * C + c], acc[c]);
        }
    }
    float4* o = (float4*)(xw + (size_t)row * C);
#pragma unroll
    for (int q = 0; q < 4; ++q)
        o[q] = make_float4(acc[4 * q + 0], acc[4 * q + 1], acc[4 * q + 2], acc[4 * q + 3]);
}

// Counting-sort pass A: per-target rank of each edge. 3.2M int atomics.
__global__ __launch_bounds__(256) void k_rank(const int* __restrict__ col,
                                              int* __restrict__ cnt,
                                              int* __restrict__ rank, int E)
{
    int e = blockIdx.x * 256 + threadIdx.x;
    if (e >= E) return;
    rank[e] = atomicAdd(&cnt[col[e]], 1);
}

// Scan 1/3: per-block (1024-elem tile) sums.
__global__ __launch_bounds__(256) void k_scan1(const int* __restrict__ cnt,
                                               int* __restrict__ bsum, int n)
{
    __shared__ int red[256];
    int t = threadIdx.x;
    int base = blockIdx.x * SCAN_TILE + t * 4;
    int s = 0;
#pragma unroll
    for (int j = 0; j < 4; ++j) { int i = base + j; if (i < n) s += cnt[i]; }
    red[t] = s;
    __syncthreads();
    for (int d = 128; d > 0; d >>= 1) {
        if (t < d) red[t] += red[t + d];
        __syncthreads();
    }
    if (t == 0) bsum[blockIdx.x] = red[0];
}

// Scan 2/3: exclusive scan of block sums (nb <= 128). One block.
__global__ __launch_bounds__(128) void k_scan2(const int* __restrict__ bsum,
                                               int* __restrict__ boff, int nb)
{
    __shared__ int sh[128];
    int t = threadIdx.x;
    int v = (t < nb) ? bsum[t] : 0;
    sh[t] = v;
    __syncthreads();
    for (int d = 1; d < 128; d <<= 1) {
        int u = (t >= d) ? sh[t - d] : 0;
        __syncthreads();
        sh[t] += u;
        __syncthreads();
    }
    if (t < nb) boff[t] = sh[t] - v;  // exclusive
}

// Scan 3/3: per-tile exclusive scan + tile offset -> starts.
__global__ __launch_bounds__(256) void k_scan3(const int* __restrict__ cnt,
                                               const int* __restrict__ boff,
                                               int* __restrict__ starts, int n)
{
    __shared__ int sh[256];
    int t = threadIdx.x;
    int base = blockIdx.x * SCAN_TILE + t * 4;
    int c0 = (base + 0 < n) ? cnt[base + 0] : 0;
    int c1 = (base + 1 < n) ? cnt[base + 1] : 0;
    int c2 = (base + 2 < n) ? cnt[base + 2] : 0;
    int c3 = (base + 3 < n) ? cnt[base + 3] : 0;
    int s = c0 + c1 + c2 + c3;
    sh[t] = s;
    __syncthreads();
    for (int d = 1; d < 256; d <<= 1) {
        int u = (t >= d) ? sh[t - d] : 0;
        __syncthreads();
        sh[t] += u;
        __syncthreads();
    }
    int off = boff[blockIdx.x] + sh[t] - s;  // exclusive within grid
    if (base + 0 < n) starts[base + 0] = off;
    if (base + 1 < n) starts[base + 1] = off + c0;
    if (base + 2 < n) starts[base + 2] = off + c0 + c1;
    if (base + 3 < n) starts[base + 3] = off + c0 + c1 + c2;
}

// Pass C: scatter source indices into CSR order. No atomics.
__global__ __launch_bounds__(256) void k_scatter(const int* __restrict__ ei,
                                                 const int* __restrict__ rank,
                                                 const int* __restrict__ starts,
                                                 int* __restrict__ srcs, int E)
{
    int e = blockIdx.x * 256 + threadIdx.x;
    if (e >= E) return;
    int r = ei[e];        // source
    int c = ei[E + e];    // target
    srcs[starts[c] + rank[e]] = r;
}

// y = xw * dinv (in place); dinv = rsqrt(cnt+1).
__global__ __launch_bounds__(256) void k_scale(float* __restrict__ xw,
                                               const int* __restrict__ cnt,
                                               float* __restrict__ dinv, int n)
{
    int i = blockIdx.x * 256 + threadIdx.x;
    if (i >= n) return;
    float di = rsqrtf((float)(cnt[i] + 1));
    dinv[i] = di;
    float4* yr = (float4*)(xw + (size_t)i * C);
#pragma unroll
    for (int q = 0; q < 4; ++q) {
        float4 v = yr[q];
        v.x *= di; v.y *= di; v.z *= di; v.w *= di;
        yr[q] = v;
    }
}

// Gather: 4 threads/node, one float4 channel-quad each. srcs read as aligned
// int4 (broadcast across the 4-lane group) -> 4 independent y loads in flight.
__global__ __launch_bounds__(256) void k_gather(const float* __restrict__ y,
                                                const int* __restrict__ srcs,
                                                const int* __restrict__ starts,
                                                const int* __restrict__ cnt,
                                                const float* __restrict__ dinv,
                                                const float* __restrict__ bg,
                                                float* __restrict__ h, int n)
{
    int tid = blockIdx.x * 256 + threadIdx.x;
    int i = tid >> 2;
    if (i >= n) return;
    int q = tid & 3;
    const float4* yv = (const float4*)y;
    float4 acc = yv[(size_t)i * 4 + q];  // self-loop term
    int beg = starts[i];
    int end = beg + cnt[i];
    int e = beg;
    int headEnd = (beg + 3) & ~3;
    if (headEnd > end) headEnd = end;
    for (; e < headEnd; ++e) {
        float4 v = yv[(size_t)srcs[e] * 4 + q];
        acc.x += v.x; acc.y += v.y; acc.z += v.z; acc.w += v.w;
    }
    for (; e + 4 <= end; e += 4) {
        int4 s4 = *(const int4*)(srcs + e);
        float4 v0 = yv[(size_t)s4.x * 4 + q];
        float4 v1 = yv[(size_t)s4.y * 4 + q];
        float4 v2 = yv[(size_t)s4.z * 4 + q];
        float4 v3 = yv[(size_t)s4.w * 4 + q];
        acc.x += v0.x + v1.x + v2.x + v3.x;
        acc.y += v0.y + v1.y + v2.y + v3.y;
        acc.z += v0.z + v1.z + v2.z + v3.z;
        acc.w += v0.w + v1.w + v2.w + v3.w;
    }
    for (; e < end; ++e) {
        float4 v = yv[(size_t)srcs[e] * 4 + q];
        acc.x += v.x; acc.y += v.y; acc.z += v.z; acc.w += v.w;
    }
    float di = dinv[i];
    const float* bq = bg + q * 4;
    float4 r;
    r.x = fmaxf(fmaf(acc.x, di, bq[0]), 0.f);
    r.y = fmaxf(fmaf(acc.y, di, bq[1]), 0.f);
    r.z = fmaxf(fmaf(acc.z, di, bq[2]), 0.f);
    r.w = fmaxf(fmaf(acc.w, di, bq[3]), 0.f);
    ((float4*)(h + (size_t)i * C))[q] = r;
}

// MLP: h1 = relu(h@W1+b1); h2 = relu(h1@W2+b2); out = sigmoid(h2@W3+b3)
__global__ __launch_bounds__(256) void k_mlp(const float* __restrict__ hbuf,
                                             const float* __restrict__ W1,
                                             const float* __restrict__ b1,
                                             const float* __restrict__ W2,
                                             const float* __restrict__ b2,
                                             const float* __restrict__ W3,
                                             const float* __restrict__ b3,
                                             float* __restrict__ out, int n)
{
    int i = blockIdx.x * 256 + threadIdx.x;
    if (i >= n) return;
    float h[16];
    const float4* hr = (const float4*)(hbuf + (size_t)i * C);
#pragma unroll
    for (int q = 0; q < 4; ++q) {
        float4 v = hr[q];
        h[4 * q + 0] = v.x; h[4 * q + 1] = v.y; h[4 * q + 2] = v.z; h[4 * q + 3] = v.w;
    }
    float h1[16];
#pragma unroll
    for (int c = 0; c < 16; ++c) {
        float s = b1[c];
#pragma unroll
        for (int k = 0; k < 16; ++k) s = fmaf(h[k], W1[k * 16 + c], s);
        h1[c] = fmaxf(s, 0.f);
    }
    float h2[32];
#pragma unroll
    for (int c = 0; c < 32; ++c) {
        float s = b2[c];
#pragma unroll
        for (int k = 0; k < 16; ++k) s = fmaf(h1[k], W2[k * 32 + c], s);
        h2[c] = fmaxf(s, 0.f);
    }
    float s = b3[0];
#pragma unroll
    for (int k = 0; k < 32; ++k) s = fmaf(h2[k], W3[k], s);
    out[i] = 1.f / (1.f + expf(-s));
}

extern "C" void kernel_launch(void* const* d_in, const int* in_sizes, int n_in,
                              void* d_out, int out_size, void* d_ws, size_t ws_size,
                              hipStream_t stream)
{
    const float* x  = (const float*)d_in[0];
    const int*   ei = (const int*)d_in[1];   // [2,E]: row at [e], col at [E+e]
    const float* Wg = (const float*)d_in[2];
    const float* bg = (const float*)d_in[3];
    const float* W1 = (const float*)d_in[4];
    const float* b1 = (const float*)d_in[5];
    const float* W2 = (const float*)d_in[6];
    const float* b2 = (const float*)d_in[7];
    const float* W3 = (const float*)d_in[8];
    const float* b3 = (const float*)d_in[9];
    float* out = (float*)d_out;

    int n = in_sizes[0] / F;   // 100000
    int E = in_sizes[1] / 2;   // 3200000

    // ws layout (16B aligned): y[n*16] | h[n*16] | rank[E] | srcs[E] |
    //                          cnt[n] | starts[n] | dinv[n] | bsum[128] | boff[128]
    char* ws = (char*)d_ws;
    size_t off = 0;
    float* y      = (float*)(ws + off); off += (size_t)n * C * sizeof(float);
    float* h      = (float*)(ws + off); off += (size_t)n * C * sizeof(float);
    int*   rank   = (int*)  (ws + off); off += (size_t)E * sizeof(int);
    int*   srcs   = (int*)  (ws + off); off += (size_t)E * sizeof(int);
    int*   cnt    = (int*)  (ws + off); off += (size_t)((n + 3) & ~3) * sizeof(int);
    int*   starts = (int*)  (ws + off); off += (size_t)((n + 3) & ~3) * sizeof(int);
    float* dinv   = (float*)(ws + off); off += (size_t)((n + 3) & ~3) * sizeof(float);
    int*   bsum   = (int*)  (ws + off); off += 128 * sizeof(int);
    int*   boff   = (int*)  (ws + off);

    int gb = (n + 255) / 256;
    int ge = (E + 255) / 256;
    int gg = (n * 4 + 255) / 256;
    int nb = (n + SCAN_TILE - 1) / SCAN_TILE;  // 98 <= 128

    k_xw<<<gb, 256, 0, stream>>>(x, Wg, y, cnt, n);
    k_rank<<<ge, 256, 0, stream>>>(ei + E, cnt, rank, E);
    k_scan1<<<nb, 256, 0, stream>>>(cnt, bsum, n);
    k_scan2<<<1, 128, 0, stream>>>(bsum, boff, nb);
    k_scan3<<<nb, 256, 0, stream>>>(cnt, boff, starts, n);
    k_scatter<<<ge, 256, 0, stream>>>(ei, rank, starts, srcs, E);
    k_scale<<<gb, 256, 0, stream>>>(y, cnt, dinv, n);
    k_gather<<<gg, 256, 0, stream>>>(y, srcs, starts, cnt, dinv, bg, h, n);
    k_mlp<<<gb, 256, 0, stream>>>(h, W1, b1, W2, b2, W3, b3, out, n);
}